// Round 10
// baseline (355.175 us; speedup 1.0000x reference)
//
#include <hip/hip_runtime.h>

typedef __bf16 bf16_t;
typedef __attribute__((ext_vector_type(8))) __bf16 bh8;
typedef __attribute__((ext_vector_type(4))) __bf16 bh4;
typedef __attribute__((ext_vector_type(4))) float f32x4;

#define DEV static __device__ __forceinline__

typedef __attribute__((address_space(3))) void lds_void;
typedef const __attribute__((address_space(1))) void glb_void;

// async global->LDS, 16B per lane; LDS dest = wave-uniform base + lane*16
DEV void async16(const bf16_t* g, bf16_t* l) {
  __builtin_amdgcn_global_load_lds((glb_void*)g, (lds_void*)l, 16, 0, 0);
}

// raw barrier (no vmcnt(0)/lgkmcnt(0) drain like __syncthreads) + compiler fence
#define GBAR() asm volatile("s_barrier" ::: "memory")
#define VMW(n) asm volatile("s_waitcnt vmcnt(" #n ")" ::: "memory")

DEV f32x4 mfma16(bh8 a, bh8 b, f32x4 c) {
  return __builtin_amdgcn_mfma_f32_16x16x32_bf16(a, b, c, 0, 0, 0);
}

// swizzled LDS addressing for [R][64] bf16 tiles (rows = 128B): physical 16B-chunk
// = logical chunk ^ mask(row). mask7 for staged tiles (matches pre-swizzled
// global source), maskP adds row-bit3 so the 4 quads' C-layout writes hit 4
// distinct chunks.
DEV const bf16_t* lds7(const bf16_t* base, int row, int c) {
  return base + row * 64 + ((c ^ (row & 7)) << 3);
}
DEV bf16_t* ldsP(bf16_t* base, int row, int c) {
  int m = (row & 7) ^ ((row >> 3) & 1);
  return base + row * 64 + ((c ^ m) << 3);
}

// ---------- helpers ----------
DEV float wave_sum(float v) {
#pragma unroll
  for (int m = 32; m > 0; m >>= 1) v += __shfl_xor(v, m, 64);
  return v;
}

// assumes blockDim.x == 256 (4 waves)
DEV float block_sum(float v, float* sbuf) {
  v = wave_sum(v);
  int wid = threadIdx.x >> 6;
  if ((threadIdx.x & 63) == 0) sbuf[wid] = v;
  __syncthreads();
  float r = sbuf[0] + sbuf[1] + sbuf[2] + sbuf[3];
  __syncthreads();
  return r;
}

// ---------- fused weight-row norms: all 5 weights in one dispatch ----------
__global__ void k_wnorm_all(const float* __restrict__ w_cond, const float* __restrict__ w_qkv,
                            const float* __restrict__ w_out, const float* __restrict__ w_mlp1,
                            const float* __restrict__ w_mlp2, float* __restrict__ s) {
  __shared__ float sbuf[4];
  int id = blockIdx.x;
  const float* W; int N, K, row;
  if (id < 1024)      { W = w_cond; N = 2048; K = 1024; row = id; }
  else if (id < 2048) { W = w_qkv;  N = 3072; K = 1024; row = id - 1024; }
  else if (id < 3072) { W = w_out;  N = 1024; K = 1024; row = id - 2048; }
  else if (id < 4096) { W = w_mlp1; N = 4096; K = 1024; row = id - 3072; }
  else                { W = w_mlp2; N = 1024; K = 4096; row = id - 4096; }
  const float4* wr = (const float4*)(W + (size_t)row * N);
  float acc = 0.f;
  for (int i = threadIdx.x; i < (N >> 2); i += 256) {
    float4 w = wr[i];
    acc += w.x*w.x + w.y*w.y + w.z*w.z + w.w*w.w;
  }
  float tot = block_sum(acc, sbuf);
  if (threadIdx.x == 0) {
    float norm = sqrtf(tot);
    s[id] = 1.0f / ((norm * sqrtf((float)N) + 1e-4f) * sqrtf((float)K));
  }
}

// ---------- fused transpose+scale+cast: Wt[n][k] = bf16(W[k][n]*s[k]) ----------
// float4 reads (16B/lane), bh4 writes (8B/lane, 128B-contiguous per 16 lanes).
__global__ void k_wtrans_all(const float* __restrict__ w_cond, const float* __restrict__ w_qkv,
                             const float* __restrict__ w_out, const float* __restrict__ w_mlp1,
                             const float* __restrict__ w_mlp2, const float* __restrict__ sall,
                             bf16_t* __restrict__ wt_cond, bf16_t* __restrict__ wt_qkv,
                             bf16_t* __restrict__ wt_out, bf16_t* __restrict__ wt_mlp1,
                             bf16_t* __restrict__ wt_mlp2) {
  __shared__ float tile[64][65];
  int id = blockIdx.x;
  const float* W; const float* s; bf16_t* Wt; int K, N, n0, k0;
  if (id < 512)       { W=w_cond; s=sall;      Wt=wt_cond; K=1024; N=2048; int l=id;      n0=(l&31)*64; k0=(l>>5)*64; }
  else if (id < 1280) { W=w_qkv;  s=sall+1024; Wt=wt_qkv;  K=1024; N=3072; int l=id-512;  n0=(l%48)*64; k0=(l/48)*64; }
  else if (id < 1536) { W=w_out;  s=sall+2048; Wt=wt_out;  K=1024; N=1024; int l=id-1280; n0=(l&15)*64; k0=(l>>4)*64; }
  else if (id < 2560) { W=w_mlp1; s=sall+3072; Wt=wt_mlp1; K=1024; N=4096; int l=id-1536; n0=(l&63)*64; k0=(l>>6)*64; }
  else                { W=w_mlp2; s=sall+4096; Wt=wt_mlp2; K=4096; N=1024; int l=id-2560; n0=(l&15)*64; k0=(l>>4)*64; }
  int t = threadIdx.x;
#pragma unroll
  for (int i = t; i < 1024; i += 256) {
    int r = i >> 4, c4 = (i & 15) << 2;
    float sc = s[k0 + r];
    float4 w = *(const float4*)(W + (size_t)(k0 + r) * N + n0 + c4);
    tile[r][c4 + 0] = w.x * sc;
    tile[r][c4 + 1] = w.y * sc;
    tile[r][c4 + 2] = w.z * sc;
    tile[r][c4 + 3] = w.w * sc;
  }
  __syncthreads();
#pragma unroll
  for (int i = t; i < 1024; i += 256) {
    int rr = i >> 4, cc = (i & 15) << 2;
    bh4 o;
    o[0] = (bf16_t)tile[cc + 0][rr];
    o[1] = (bf16_t)tile[cc + 1][rr];
    o[2] = (bf16_t)tile[cc + 2][rr];
    o[3] = (bf16_t)tile[cc + 3][rr];
    *(bh4*)(Wt + (size_t)(n0 + rr) * K + k0 + cc) = o;
  }
}

// ---------- conditioning: gs[b][j] = (silu(c[b])/0.596) . wn_cond[:,j] ----------
__global__ void k_cond(const float* __restrict__ c, const bf16_t* __restrict__ wt,
                       float* __restrict__ gs) {
  __shared__ float cc[4][1024];
  int t = threadIdx.x;
  for (int i = t; i < 4096; i += 256) {
    int b = i >> 10, col = i & 1023;
    float x = c[b * 1024 + col];
    float sig = 1.f / (1.f + __expf(-x));
    cc[b][col] = x * sig * (1.f / 0.596f);
  }
  __syncthreads();
  int wid = t >> 6, lane = t & 63;
  int j = blockIdx.x * 4 + wid;
  const bf16_t* wr = wt + (size_t)j * 1024;
  float acc0 = 0, acc1 = 0, acc2 = 0, acc3 = 0;
  for (int i = lane; i < 1024; i += 64) {
    float w = (float)wr[i];
    acc0 += cc[0][i] * w; acc1 += cc[1][i] * w;
    acc2 += cc[2][i] * w; acc3 += cc[3][i] * w;
  }
  float v0 = wave_sum(acc0), v1 = wave_sum(acc1), v2 = wave_sum(acc2), v3 = wave_sum(acc3);
  if (lane == 0) {
    gs[0 * 2048 + j] = v0; gs[1 * 2048 + j] = v1;
    gs[2 * 2048 + j] = v2; gs[3 * 2048 + j] = v3;
  }
}

// ---------- xc = bf16(pixel_norm(x)*(1+gain)+shift), one block per row ----------
__global__ void k_xcond(const float* __restrict__ x, const float* __restrict__ gs,
                        bf16_t* __restrict__ xc) {
  __shared__ float sbuf[4];
  int row = blockIdx.x, b = row >> 10, t = threadIdx.x;
  float4 v = ((const float4*)(x + (size_t)row * 1024))[t];
  float ss = v.x*v.x + v.y*v.y + v.z*v.z + v.w*v.w;
  float tot = block_sum(ss, sbuf);
  float r = rsqrtf(tot * (1.f/1024.f) + 1e-4f);
  float4 g  = ((const float4*)(gs + b * 2048))[t];
  float4 sh = ((const float4*)(gs + b * 2048 + 1024))[t];
  bh4 o;
  o[0] = (bf16_t)(v.x * r * (1.f + g.x) + sh.x);
  o[1] = (bf16_t)(v.y * r * (1.f + g.y) + sh.y);
  o[2] = (bf16_t)(v.z * r * (1.f + g.z) + sh.z);
  o[3] = (bf16_t)(v.w * r * (1.f + g.w) + sh.w);
  *(bh4*)(xc + (size_t)row * 1024 + t * 4) = o;
}

// ---------- 256x256 8-phase bf16 MFMA GEMM (R1 schedule, measured best) ----------
//   ph1: 12 ds_read | stage A(kt+1)h0 -> rb^1
//   ph2:  4 ds_read | stage A(kt+1)h1 -> rb^1
//   ph3:  8 ds_read | stage B(kt+2)h0 -> rb   [B[rb] last read ph2]
//   ph4:  0 ds_read | stage B(kt+2)h1 -> rb
//   end ph4: vmcnt(4) -- A(kt+1)+B(kt+1) landed; B(kt+2)'s 4 loads in flight.
__global__ __launch_bounds__(512, 2) void k_gemm8(const bf16_t* __restrict__ A,
                                                  const bf16_t* __restrict__ Bt,
                                                  bf16_t* __restrict__ C,
                                                  int M, int N, int K, int klen) {
  __shared__ __attribute__((aligned(16))) bf16_t As[2][2][256][32];
  __shared__ __attribute__((aligned(16))) bf16_t Bs[2][2][256][32];
  // bijective XCD swizzle (requires nwg % 8 == 0; all our grids satisfy this)
  const int ntn = gridDim.x;
  const unsigned flat = blockIdx.x + ntn * blockIdx.y;
  const unsigned q = (ntn * gridDim.y) >> 3;
  const unsigned wg = (flat & 7) * q + (flat >> 3);
  const int m0 = (int)(wg / (unsigned)ntn) * 256;
  const int n0 = (int)(wg % (unsigned)ntn) * 256;
  const size_t kbeg = (size_t)blockIdx.z * klen;
  C += (size_t)blockIdx.z * M * N;
  const int t = threadIdx.x, lane = t & 63;
  const int wm = (t >> 6) >> 2, wn = (t >> 6) & 3;
  const int l15 = lane & 15, quad = lane >> 4;
  const int q8 = (quad ^ ((l15 >> 2) & 2)) * 8;   // swizzled slot of logical k-chunk
  const int rA = wm * 128 + l15;
  const int rB = wn * 64 + l15;
  const int sr = t >> 2;
  const int sc = ((t & 3) << 3) ^ ((t & 32) >> 1);   // ^16 when row bit3 set
  const int swv = (t >> 6) * 512;                    // wave-uniform LDS elem base
  const bf16_t* AgS = A + (size_t)(m0 + sr) * K + kbeg + sc;
  const bf16_t* BgS = Bt + (size_t)(n0 + sr) * K + kbeg + sc;
  const size_t rstep = (size_t)128 * K;
  const int NT = klen >> 6;
  f32x4 acc[8][4] = {};

#define STG_A(kt_, h_, bb_) { const bf16_t* g = AgS + (kt_) * 64 + (h_) * 32; \
    bf16_t* l = &As[bb_][h_][0][0] + swv; async16(g, l); async16(g + rstep, l + 4096); }
#define STG_B(kt_, h_, bb_) { const bf16_t* g = BgS + (kt_) * 64 + (h_) * 32; \
    bf16_t* l = &Bs[bb_][h_][0][0] + swv; async16(g, l); async16(g + rstep, l + 4096); }

  // prologue: B(0), A(0) -> buf0; B(1) -> buf1; wait all but B(1)'s 4 loads
  STG_B(0, 0, 0); STG_B(0, 1, 0);
  STG_A(0, 0, 0); STG_A(0, 1, 0);
  if (NT > 1) { STG_B(1, 0, 1); STG_B(1, 1, 1); VMW(4); } else { VMW(0); }
  GBAR();

  for (int kt = 0; kt < NT; ++kt) {
    const int bb = kt & 1;
    bh8 a[4][2], b[4][2];
    // ---- phase 1
#pragma unroll
    for (int m = 0; m < 4; ++m)
#pragma unroll
      for (int kc = 0; kc < 2; ++kc)
        a[m][kc] = *(const bh8*)&As[bb][kc][rA + m * 16][q8];
#pragma unroll
    for (int n = 0; n < 2; ++n)
#pragma unroll
      for (int kc = 0; kc < 2; ++kc)
        b[n][kc] = *(const bh8*)&Bs[bb][kc][rB + n * 16][q8];
    if (kt + 1 < NT) STG_A(kt + 1, 0, bb ^ 1);
    GBAR();
    __builtin_amdgcn_s_setprio(1);
#pragma unroll
    for (int m = 0; m < 4; ++m)
#pragma unroll
      for (int n = 0; n < 2; ++n)
#pragma unroll
        for (int kc = 0; kc < 2; ++kc)
          acc[m][n] = mfma16(a[m][kc], b[n][kc], acc[m][n]);
    __builtin_amdgcn_s_setprio(0);
    GBAR();
    // ---- phase 2
#pragma unroll
    for (int n = 0; n < 2; ++n)
#pragma unroll
      for (int kc = 0; kc < 2; ++kc)
        b[2 + n][kc] = *(const bh8*)&Bs[bb][kc][rB + (2 + n) * 16][q8];
    if (kt + 1 < NT) STG_A(kt + 1, 1, bb ^ 1);
    GBAR();
    __builtin_amdgcn_s_setprio(1);
#pragma unroll
    for (int m = 0; m < 4; ++m)
#pragma unroll
      for (int n = 0; n < 2; ++n)
#pragma unroll
        for (int kc = 0; kc < 2; ++kc)
          acc[m][2 + n] = mfma16(a[m][kc], b[2 + n][kc], acc[m][2 + n]);
    __builtin_amdgcn_s_setprio(0);
    GBAR();
    // ---- phase 3
#pragma unroll
    for (int m = 0; m < 4; ++m)
#pragma unroll
      for (int kc = 0; kc < 2; ++kc)
        a[m][kc] = *(const bh8*)&As[bb][kc][rA + 64 + m * 16][q8];
    if (kt + 2 < NT) STG_B(kt + 2, 0, bb);
    GBAR();
    __builtin_amdgcn_s_setprio(1);
#pragma unroll
    for (int m = 0; m < 4; ++m)
#pragma unroll
      for (int n = 0; n < 2; ++n)
#pragma unroll
        for (int kc = 0; kc < 2; ++kc)
          acc[4 + m][n] = mfma16(a[m][kc], b[n][kc], acc[4 + m][n]);
    __builtin_amdgcn_s_setprio(0);
    GBAR();
    // ---- phase 4
    if (kt + 2 < NT) STG_B(kt + 2, 1, bb);
    __builtin_amdgcn_s_setprio(1);
#pragma unroll
    for (int m = 0; m < 4; ++m)
#pragma unroll
      for (int n = 0; n < 2; ++n)
#pragma unroll
        for (int kc = 0; kc < 2; ++kc)
          acc[4 + m][2 + n] = mfma16(a[m][kc], b[2 + n][kc], acc[4 + m][2 + n]);
    __builtin_amdgcn_s_setprio(0);
    if (kt + 2 < NT) { VMW(4); } else { VMW(0); }
    GBAR();
  }
#undef STG_A
#undef STG_B

  const int cm = m0 + wm * 128 + quad * 4;
  const int cn = n0 + wn * 64 + l15;
#pragma unroll
  for (int m = 0; m < 8; ++m)
#pragma unroll
    for (int n = 0; n < 4; ++n)
#pragma unroll
      for (int r2 = 0; r2 < 4; ++r2)
        C[(size_t)(cm + m * 16 + r2) * N + cn + n * 16] = (bf16_t)acc[m][n][r2];
}

// ---------- 128x128-tile 2-phase GEMM (64 KiB LDS -> 2 blocks/CU) ----------
// 256 threads = 4 waves (2Mx2N); per-wave output 64x64; BK=64.
// Used where grid >= 512 blocks (cross-block wave overlap hides barrier stalls)
// or where split-K would force extra partial traffic. Schedule per K-tile:
//   ph1: 16 ds_read | stage A(kt+1) h0+h1 -> rb^1; BAR; 16 MFMA; BAR
//   ph2: stage B(kt+2) h0+h1 -> rb [B[rb] reads all in ph1]; 16 MFMA; vmcnt(4); BAR
__global__ __launch_bounds__(256, 2) void k_gemm2ph(const bf16_t* __restrict__ A,
                                                    const bf16_t* __restrict__ Bt,
                                                    bf16_t* __restrict__ C,
                                                    int M, int N, int K) {
  __shared__ __attribute__((aligned(16))) bf16_t As[2][2][128][32];
  __shared__ __attribute__((aligned(16))) bf16_t Bs[2][2][128][32];
  const int ntn = gridDim.x;
  const unsigned flat = blockIdx.x + ntn * blockIdx.y;
  const unsigned q = (ntn * gridDim.y) >> 3;
  const unsigned wg = (flat & 7) * q + (flat >> 3);
  const int m0 = (int)(wg / (unsigned)ntn) * 128;
  const int n0 = (int)(wg % (unsigned)ntn) * 128;
  const int t = threadIdx.x, lane = t & 63;
  const int wm = (t >> 6) >> 1, wn = (t >> 6) & 1;
  const int l15 = lane & 15, quad = lane >> 4;
  const int q8 = (quad ^ ((l15 >> 2) & 2)) * 8;
  const int rA = wm * 64 + l15;
  const int rB = wn * 64 + l15;
  const int sr = t >> 2;                             // 0..63
  const int sc = ((t & 3) << 3) ^ ((t & 32) >> 1);   // ^16 when row bit3 set
  const int swv = (t >> 6) * 512;                    // wave-uniform LDS elem base
  const bf16_t* AgS = A + (size_t)(m0 + sr) * K + sc;
  const bf16_t* BgS = Bt + (size_t)(n0 + sr) * K + sc;
  const size_t rstep = (size_t)64 * K;
  const int NT = K >> 6;
  f32x4 acc[4][4] = {};

#define STG_A(kt_, h_, bb_) { const bf16_t* g = AgS + (kt_) * 64 + (h_) * 32; \
    bf16_t* l = &As[bb_][h_][0][0] + swv; async16(g, l); async16(g + rstep, l + 2048); }
#define STG_B(kt_, h_, bb_) { const bf16_t* g = BgS + (kt_) * 64 + (h_) * 32; \
    bf16_t* l = &Bs[bb_][h_][0][0] + swv; async16(g, l); async16(g + rstep, l + 2048); }

  // prologue: A(0),B(0) -> buf0; B(1) -> buf1; keep B(1)'s 4 calls in flight
  STG_B(0, 0, 0); STG_B(0, 1, 0);
  STG_A(0, 0, 0); STG_A(0, 1, 0);
  if (NT > 1) { STG_B(1, 0, 1); STG_B(1, 1, 1); VMW(4); } else { VMW(0); }
  GBAR();

  for (int kt = 0; kt < NT; ++kt) {
    const int bb = kt & 1;
    bh8 a[4][2], b[4][2];
    // ---- phase 1: all 16 ds_read; stage A(kt+1) -> rb^1
#pragma unroll
    for (int m = 0; m < 4; ++m)
#pragma unroll
      for (int kc = 0; kc < 2; ++kc)
        a[m][kc] = *(const bh8*)&As[bb][kc][rA + m * 16][q8];
#pragma unroll
    for (int n = 0; n < 4; ++n)
#pragma unroll
      for (int kc = 0; kc < 2; ++kc)
        b[n][kc] = *(const bh8*)&Bs[bb][kc][rB + n * 16][q8];
    if (kt + 1 < NT) { STG_A(kt + 1, 0, bb ^ 1); STG_A(kt + 1, 1, bb ^ 1); }
    GBAR();
    __builtin_amdgcn_s_setprio(1);
#pragma unroll
    for (int m = 0; m < 4; ++m)
#pragma unroll
      for (int n = 0; n < 2; ++n)
#pragma unroll
        for (int kc = 0; kc < 2; ++kc)
          acc[m][n] = mfma16(a[m][kc], b[n][kc], acc[m][n]);
    __builtin_amdgcn_s_setprio(0);
    GBAR();
    // ---- phase 2: stage B(kt+2) -> rb (B[rb] reads all done ph1, barrier-separated)
    if (kt + 2 < NT) { STG_B(kt + 2, 0, bb); STG_B(kt + 2, 1, bb); }
    __builtin_amdgcn_s_setprio(1);
#pragma unroll
    for (int m = 0; m < 4; ++m)
#pragma unroll
      for (int n = 0; n < 2; ++n)
#pragma unroll
        for (int kc = 0; kc < 2; ++kc)
          acc[m][2 + n] = mfma16(a[m][kc], b[2 + n][kc], acc[m][2 + n]);
    __builtin_amdgcn_s_setprio(0);
    if (kt + 2 < NT) { VMW(4); } else { VMW(0); }
    GBAR();
  }
#undef STG_A
#undef STG_B

  const int cm = m0 + wm * 64 + quad * 4;
  const int cn = n0 + wn * 64 + l15;
#pragma unroll
  for (int m = 0; m < 4; ++m)
#pragma unroll
    for (int n = 0; n < 4; ++n)
#pragma unroll
      for (int r2 = 0; r2 < 4; ++r2)
        C[(size_t)(cm + m * 16 + r2) * N + cn + n * 16] = (bf16_t)acc[m][n][r2];
}

// ---------- qkv (bf16 in): pixel_norm per 1024-chunk + per-head L2 norm ----------
// writes qh/kh [B,NH,N,DH]; V is NOT materialized -- only its per-row scale rsv[row]
// (k_vtrans applies it while transposing straight out of the qkv buffer).
__global__ void k_qkvnorm(const bf16_t* __restrict__ qkv, bf16_t* __restrict__ qo,
                          bf16_t* __restrict__ ko, float* __restrict__ rsv) {
  __shared__ float sbuf[4];
  const int row = blockIdx.x, b = row >> 10, n = row & 1023, t = threadIdx.x;
  const bf16_t* rp = qkv + (size_t)row * 3072;
  bh4 q4 = *(const bh4*)(rp + t * 4);
  bh4 k4 = *(const bh4*)(rp + 1024 + t * 4);
  bh4 v4 = *(const bh4*)(rp + 2048 + t * 4);
  float4 q = {(float)q4[0], (float)q4[1], (float)q4[2], (float)q4[3]};
  float4 k = {(float)k4[0], (float)k4[1], (float)k4[2], (float)k4[3]};
  float4 v = {(float)v4[0], (float)v4[1], (float)v4[2], (float)v4[3]};
  float sq = q.x*q.x + q.y*q.y + q.z*q.z + q.w*q.w;
  float sk = k.x*k.x + k.y*k.y + k.z*k.z + k.w*k.w;
  float sv = v.x*v.x + v.y*v.y + v.z*v.z + v.w*v.w;
  float tq = block_sum(sq, sbuf);
  float tk = block_sum(sk, sbuf);
  float tv = block_sum(sv, sbuf);
  float rq = rsqrtf(tq * (1.f/1024.f) + 1e-4f);
  float rk = rsqrtf(tk * (1.f/1024.f) + 1e-4f);
  float rv = rsqrtf(tv * (1.f/1024.f) + 1e-4f);
  float hq = sq, hk = sk;   // per-head sums: 16 consecutive threads = one head (within a wave)
#pragma unroll
  for (int m = 1; m < 16; m <<= 1) { hq += __shfl_xor(hq, m, 64); hk += __shfl_xor(hk, m, 64); }
  float qs = rq * rsqrtf(rq*rq*hq + 1e-6f);
  float ks = rk * rsqrtf(rk*rk*hk + 1e-6f);
  int h = t >> 4, d = (t & 15) * 4;
  size_t base = ((size_t)(b * 16 + h) * 1024 + n) * 64 + d;
  bh4 oq, okk;
  oq[0]=(bf16_t)(q.x*qs); oq[1]=(bf16_t)(q.y*qs); oq[2]=(bf16_t)(q.z*qs); oq[3]=(bf16_t)(q.w*qs);
  okk[0]=(bf16_t)(k.x*ks); okk[1]=(bf16_t)(k.y*ks); okk[2]=(bf16_t)(k.z*ks); okk[3]=(bf16_t)(k.w*ks);
  *(bh4*)(qo + base) = oq;
  *(bh4*)(ko + base) = okk;
  if (t == 0) rsv[row] = rv;
}

// ---------- V transpose + pixel_norm: vt[bh][d][n] = bf16(qkv_v[b][n][h*64+d] * rsv[b*1024+n]) ----------
__global__ void k_vtrans(const bf16_t* __restrict__ qkv, const float* __restrict__ rsv,
                         bf16_t* __restrict__ vt) {
  __shared__ bf16_t tile[64][72];
  const int n0 = blockIdx.x * 64, bh = blockIdx.y;
  const int b = bh >> 4, h = bh & 15;
  const int t = threadIdx.x;
  const bf16_t* src = qkv + ((size_t)(b * 1024 + n0)) * 3072 + 2048 + h * 64;
#pragma unroll
  for (int i = t; i < 512; i += 256) {
    int r = i >> 3, p = (i & 7) * 8;
    float sc = rsv[b * 1024 + n0 + r];
    bh8 vv = *(const bh8*)(src + (size_t)r * 3072 + p);
    bh8 o8;
#pragma unroll
    for (int j = 0; j < 8; j++) o8[j] = (bf16_t)((float)vv[j] * sc);
    *(bh8*)&tile[r][p] = o8;
  }
  __syncthreads();
  bf16_t* dst = vt + (size_t)bh * 64 * 1024 + n0;
#pragma unroll
  for (int i = t; i < 512; i += 256) {
    int d = i & 63, nch = (i >> 6) * 8;
    bh8 o;
#pragma unroll
    for (int j = 0; j < 8; j++) o[j] = tile[nch + j][d];
    *(bh8*)(dst + (size_t)d * 1024 + nch) = o;
  }
}

// ---------- attention v2: Q-tile 128, async-LDS double-buffered K/V, XOR-swizzled tiles ----------
__global__ __launch_bounds__(256, 2) void k_attn(const bf16_t* __restrict__ Q,
                                                 const bf16_t* __restrict__ K,
                                                 const bf16_t* __restrict__ Vt_g,
                                                 bf16_t* __restrict__ O) {
  __shared__ __attribute__((aligned(16))) bf16_t Qs[128][64];
  __shared__ __attribute__((aligned(16))) bf16_t Ks[2][64][64];
  __shared__ __attribute__((aligned(16))) bf16_t Vt[2][64][64];   // [dh][kv]
  __shared__ __attribute__((aligned(16))) bf16_t Ps[128][64];
  const unsigned flat = blockIdx.x + 8u * blockIdx.y;   // grid = (8, 64)
  const int qt = (int)((flat >> 3) & 7);
  const int bh = (int)((flat & 7) * 8 + (flat >> 6));
  const int b = bh >> 4, h = bh & 15;
  const int t = threadIdx.x, lane = t & 63, wid = t >> 6;
  const int l15 = lane & 15, quad = lane >> 4;
  const int strip = wid * 32;
  const int srow = t >> 3;                       // 0..31 per 32-row group
  const int scol = ((t & 7) ^ (srow & 7)) << 3;  // elems
  const int swv = wid * 512;                     // wave-uniform LDS elem base (8 rows)
  const bf16_t* Qg = Q + ((size_t)bh * 1024 + qt * 128) * 64;
  const bf16_t* Kg = K + (size_t)bh * 1024 * 64;
  const bf16_t* Vg = Vt_g + (size_t)bh * 64 * 1024;   // [dh][n]

  // prologue: stage Q (4 calls), K0+V0 (4 calls); drain; barrier
#pragma unroll
  for (int c2 = 0; c2 < 4; ++c2)
    async16(Qg + (size_t)(c2 * 32 + srow) * 64 + scol, &Qs[0][0] + c2 * 2048 + swv);
#pragma unroll
  for (int r0 = 0; r0 < 64; r0 += 32) {
    async16(Kg + (size_t)(r0 + srow) * 64 + scol, &Ks[0][0][0] + r0 * 64 + swv);
    async16(Vg + (size_t)(r0 + srow) * 1024 + scol, &Vt[0][0][0] + r0 * 64 + swv);
  }
  VMW(0);
  GBAR();

  f32x4 o[2][4] = {};
  float rs[2][4] = {{}, {}};
  for (int kt = 0; kt < 16; ++kt) {
    const int bb = kt & 1;
    const int kv0 = kt * 64;
    if (kt < 15) {
#pragma unroll
      for (int r0 = 0; r0 < 64; r0 += 32) {
        async16(Kg + (size_t)(kv0 + 64 + r0 + srow) * 64 + scol,
                &Ks[bb ^ 1][0][0] + r0 * 64 + swv);
        async16(Vg + (size_t)(r0 + srow) * 1024 + kv0 + 64 + scol,
                &Vt[bb ^ 1][0][0] + r0 * 64 + swv);
      }
    }
    // ---- QK^T (this wave's 32-row strip vs 64 kv rows)
    f32x4 s[2][4] = {};
    bh8 aq[2][2], bk[4][2];
#pragma unroll
    for (int rf = 0; rf < 2; ++rf)
#pragma unroll
      for (int kc = 0; kc < 2; ++kc)
        aq[rf][kc] = *(const bh8*)lds7(&Qs[0][0], strip + rf * 16 + l15, kc * 4 + quad);
#pragma unroll
    for (int j = 0; j < 4; ++j)
#pragma unroll
      for (int kc = 0; kc < 2; ++kc)
        bk[j][kc] = *(const bh8*)lds7(&Ks[bb][0][0], j * 16 + l15, kc * 4 + quad);
    __builtin_amdgcn_s_setprio(1);
#pragma unroll
    for (int rf = 0; rf < 2; ++rf)
#pragma unroll
      for (int j = 0; j < 4; ++j)
#pragma unroll
        for (int kc = 0; kc < 2; ++kc)
          s[rf][j] = mfma16(aq[rf][kc], bk[j][kc], s[rf][j]);
    __builtin_amdgcn_s_setprio(0);
    // ---- P = exp(S/8) -> Ps (swizzled, wave-local strip); rs from bf16 P
#pragma unroll
    for (int rf = 0; rf < 2; ++rf)
#pragma unroll
      for (int j = 0; j < 4; ++j)
#pragma unroll
        for (int r = 0; r < 4; ++r) {
          float p = __expf(s[rf][j][r] * 0.125f);
          bf16_t pb = (bf16_t)p;
          rs[rf][r] += (float)pb;
          int prow = strip + rf * 16 + quad * 4 + r;
          ldsP(&Ps[0][0], prow, j * 2 + (l15 >> 3))[l15 & 7] = pb;
        }
    // ---- O += P @ V (wave reads only its own Ps strip: in-order LDS, no barrier)
    bh8 ap[2][2], bv[4][2];
#pragma unroll
    for (int rf = 0; rf < 2; ++rf)
#pragma unroll
      for (int kc = 0; kc < 2; ++kc)
        ap[rf][kc] = *(const bh8*)ldsP(&Ps[0][0], strip + rf * 16 + l15, kc * 4 + quad);
#pragma unroll
    for (int j = 0; j < 4; ++j)
#pragma unroll
      for (int kc = 0; kc < 2; ++kc)
        bv[j][kc] = *(const bh8*)lds7(&Vt[bb][0][0], j * 16 + l15, kc * 4 + quad);
    __builtin_amdgcn_s_setprio(1);
#pragma unroll
    for (int rf = 0; rf < 2; ++rf)
#pragma unroll
      for (int j = 0; j < 4; ++j)
#pragma unroll
        for (int kc = 0; kc < 2; ++kc)
          o[rf][j] = mfma16(ap[rf][kc], bv[j][kc], o[rf][j]);
    __builtin_amdgcn_s_setprio(0);
    if (kt < 15) { VMW(0); GBAR(); }
  }
  // ---- finalize: rowsum over the 16 column-lanes; O rows match rs rows
#pragma unroll
  for (int rf = 0; rf < 2; ++rf)
#pragma unroll
    for (int r = 0; r < 4; ++r) {
      float v = rs[rf][r];
      v += __shfl_xor(v, 1, 64); v += __shfl_xor(v, 2, 64);
      v += __shfl_xor(v, 4, 64); v += __shfl_xor(v, 8, 64);
      float inv = 1.f / v;
      int n = qt * 128 + strip + rf * 16 + quad * 4 + r;
#pragma unroll
      for (int j = 0; j < 4; ++j)
        O[((size_t)b * 1024 + n) * 1024 + h * 64 + j * 16 + l15] = (bf16_t)(o[rf][j][r] * inv);
    }
}

// ---------- x1 = mp_add(x, pixel_norm(y)*exp(ag)); xc2 = bf16(...)  [single partial] ----------
__global__ void k_amerge(const bf16_t* __restrict__ y, const float* __restrict__ x,
                         const float* __restrict__ gs, const float* __restrict__ again,
                         bf16_t* __restrict__ x1, bf16_t* __restrict__ xc2) {
  __shared__ float sbuf[4];
  int row = blockIdx.x, b = row >> 10, t = threadIdx.x;
  bh4 a = *(const bh4*)(y + (size_t)row * 1024 + t * 4);
  float4 yv = {(float)a[0], (float)a[1], (float)a[2], (float)a[3]};
  float4 xv = ((const float4*)(x + (size_t)row * 1024))[t];
  float ss = yv.x*yv.x + yv.y*yv.y + yv.z*yv.z + yv.w*yv.w;
  float tot = block_sum(ss, sbuf);
  float r = rsqrtf(tot * (1.f/1024.f) + 1e-4f);
  float ag = __expf(again[0]);
  const float C1 = 0.7f / 0.76157731059f, C2 = 0.3f / 0.76157731059f; // /sqrt(0.58)
  float4 xo;
  xo.x = C1 * xv.x + C2 * (yv.x * r * ag);
  xo.y = C1 * xv.y + C2 * (yv.y * r * ag);
  xo.z = C1 * xv.z + C2 * (yv.z * r * ag);
  xo.w = C1 * xv.w + C2 * (yv.w * r * ag);
  bh4 x1o;
  x1o[0] = (bf16_t)xo.x; x1o[1] = (bf16_t)xo.y; x1o[2] = (bf16_t)xo.z; x1o[3] = (bf16_t)xo.w;
  *(bh4*)(x1 + (size_t)row * 1024 + t * 4) = x1o;
  float ss1 = xo.x*xo.x + xo.y*xo.y + xo.z*xo.z + xo.w*xo.w;
  float tot1 = block_sum(ss1, sbuf);
  float r1 = rsqrtf(tot1 * (1.f/1024.f) + 1e-4f);
  float4 g  = ((const float4*)(gs + b * 2048))[t];
  float4 sh = ((const float4*)(gs + b * 2048 + 1024))[t];
  bh4 o;
  o[0] = (bf16_t)(xo.x * r1 * (1.f + g.x) + sh.x);
  o[1] = (bf16_t)(xo.y * r1 * (1.f + g.y) + sh.y);
  o[2] = (bf16_t)(xo.z * r1 * (1.f + g.z) + sh.z);
  o[3] = (bf16_t)(xo.w * r1 * (1.f + g.w) + sh.w);
  *(bh4*)(xc2 + (size_t)row * 1024 + t * 4) = o;
}

// ---------- h = bf16(mp_silu(pixel_norm(hf))) over 4096-wide rows, bf16 in ----------
__global__ void k_mlpnorm(const bf16_t* __restrict__ hf, bf16_t* __restrict__ hb) {
  __shared__ float sbuf[4];
  int row = blockIdx.x, t = threadIdx.x;
  const bf16_t* rp = hf + (size_t)row * 4096;
  float4 v[4]; float ss = 0.f;
#pragma unroll
  for (int i = 0; i < 4; i++) {
    bh4 bv = *(const bh4*)(rp + (t + 256 * i) * 4);
    v[i].x = (float)bv[0]; v[i].y = (float)bv[1]; v[i].z = (float)bv[2]; v[i].w = (float)bv[3];
    ss += v[i].x*v[i].x + v[i].y*v[i].y + v[i].z*v[i].z + v[i].w*v[i].w;
  }
  float tot = block_sum(ss, sbuf);
  float r = rsqrtf(tot * (1.f/4096.f) + 1e-4f);
#pragma unroll
  for (int i = 0; i < 4; i++) {
    float a[4] = {v[i].x, v[i].y, v[i].z, v[i].w};
    bh4 o;
#pragma unroll
    for (int j = 0; j < 4; j++) {
      float u = a[j] * r;
      float sig = 1.f / (1.f + __expf(-u));
      o[j] = (bf16_t)(u * sig * (1.f / 0.596f));
    }
    *(bh4*)(hb + (size_t)row * 4096 + (t + 256 * i) * 4) = o;
  }
}

// ---------- out = mp_add(x1, pixel_norm(sum of 4 partials)*exp(mg)) ----------
__global__ void k_fmerge(const bf16_t* __restrict__ y, const bf16_t* __restrict__ x1,
                         const float* __restrict__ mgain, float* __restrict__ out) {
  __shared__ float sbuf[4];
  int row = blockIdx.x, t = threadIdx.x;
  const size_t PS = (size_t)4096 * 1024;
  float4 yv = {0.f, 0.f, 0.f, 0.f};
#pragma unroll
  for (int p = 0; p < 4; p++) {
    bh4 yp = *(const bh4*)(y + p * PS + (size_t)row * 1024 + t * 4);
    yv.x += (float)yp[0]; yv.y += (float)yp[1]; yv.z += (float)yp[2]; yv.w += (float)yp[3];
  }
  bh4 xb = *(const bh4*)(x1 + (size_t)row * 1024 + t * 4);
  float4 xv = {(float)xb[0], (float)xb[1], (float)xb[2], (float)xb[3]};
  float ss = yv.x*yv.x + yv.y*yv.y + yv.z*yv.z + yv.w*yv.w;
  float tot = block_sum(ss, sbuf);
  float r = rsqrtf(tot * (1.f/1024.f) + 1e-4f);
  float mg = __expf(mgain[0]);
  const float C1 = 0.7f / 0.76157731059f, C2 = 0.3f / 0.76157731059f;
  float4 o;
  o.x = C1 * xv.x + C2 * (yv.x * r * mg);
  o.y = C1 * xv.y + C2 * (yv.y * r * mg);
  o.z = C1 * xv.z + C2 * (yv.z * r * mg);
  o.w = C1 * xv.w + C2 * (yv.w * r * mg);
  ((float4*)(out + (size_t)row * 1024))[t] = o;
}

// ---------- launch ----------
extern "C" void kernel_launch(void* const* d_in, const int* in_sizes, int n_in,
                              void* d_out, int out_size, void* d_ws, size_t ws_size,
                              hipStream_t stream) {
  const float* x      = (const float*)d_in[0];
  const float* c      = (const float*)d_in[1];
  const float* w_cond = (const float*)d_in[2];
  const float* w_qkv  = (const float*)d_in[3];
  const float* w_out  = (const float*)d_in[4];
  const float* w_mlp1 = (const float*)d_in[5];
  const float* w_mlp2 = (const float*)d_in[6];
  const float* again  = (const float*)d_in[7];
  const float* mgain  = (const float*)d_in[8];
  float* out = (float*)d_out;
  char* ws = (char*)d_ws;

  // ws layout (bytes)
  bf16_t* wt_cond = (bf16_t*)(ws + 0);                    //  4 MB [2048,1024]
  bf16_t* wt_qkv  = (bf16_t*)(ws + 4194304);              //  6 MB [3072,1024]
  bf16_t* wt_out  = (bf16_t*)(ws + 10485760);             //  2 MB [1024,1024]
  bf16_t* wt_mlp1 = (bf16_t*)(ws + 12582912);             //  8 MB [4096,1024]
  bf16_t* wt_mlp2 = (bf16_t*)(ws + 20971520);             //  8 MB [1024,4096]
  float*  sn      = (float*)(ws + 29360128);              //  32 KB (5 scale arrays, packed)
  float*  gs      = (float*)(ws + 29392896);              //  32 KB [4,2048]
  bf16_t* xc      = (bf16_t*)(ws + 29425664);             //  8 MB (xc, later xc2)
  bf16_t* qh      = (bf16_t*)(ws + 37814272);             //  8 MB
  bf16_t* kh      = (bf16_t*)(ws + 46202880);             //  8 MB
  float*  rsv     = (float*)(ws + 54591488);              //  16 KB (per-row V scales)
  bf16_t* xattn   = (bf16_t*)(ws + 62980096);             //  8 MB
  bf16_t* hb      = (bf16_t*)(ws + 37814272);             // 32 MB = qh..xattn reused after consumed
  bf16_t* x1      = (bf16_t*)(ws + 71368704);             //  8 MB (bf16 residual)
  bf16_t* vt      = (bf16_t*)(ws + 79757312);             //  8 MB (V^T [bh][dh][n])
  bf16_t* buf_b   = (bf16_t*)(ws + 88145920);             // 32 MB bf16: qkv / partials / h

  // weight prep (re-done every call: ws is re-poisoned by harness)
  k_wnorm_all<<<8192, 256, 0, stream>>>(w_cond, w_qkv, w_out, w_mlp1, w_mlp2, sn);
  k_wtrans_all<<<3584, 256, 0, stream>>>(w_cond, w_qkv, w_out, w_mlp1, w_mlp2, sn,
                                         wt_cond, wt_qkv, wt_out, wt_mlp1, wt_mlp2);

  // conditioning
  k_cond<<<512, 256, 0, stream>>>(c, wt_cond, gs);
  // attention branch
  k_xcond<<<4096, 256, 0, stream>>>(x, gs, xc);
  k_gemm8<<<dim3(12, 16, 1), 512, 0, stream>>>(xc, wt_qkv, buf_b, 4096, 3072, 1024, 1024);
  k_qkvnorm<<<4096, 256, 0, stream>>>(buf_b, qh, kh, rsv);
  k_vtrans<<<dim3(16, 64), 256, 0, stream>>>(buf_b, rsv, vt);
  k_attn<<<dim3(8, 64), 256, 0, stream>>>(qh, kh, vt, xattn);
  // out-projection: 128x128-tile, no split-K, full fill -> single 8 MB output
  k_gemm2ph<<<dim3(8, 32), 256, 0, stream>>>(xattn, wt_out, buf_b, 4096, 1024, 1024);
  k_amerge<<<4096, 256, 0, stream>>>(buf_b, x, gs, again, x1, xc);
  // MLP branch -- A/B experiment: mlp1 via 128^2 2-blocks/CU kernel (1024 blocks),
  // qkv above stays on k_gemm8 as the same-run control.
  k_gemm2ph<<<dim3(32, 32), 256, 0, stream>>>(xc, wt_mlp1, buf_b, 4096, 4096, 1024);
  k_mlpnorm<<<4096, 256, 0, stream>>>(buf_b, hb);
  k_gemm8<<<dim3(4, 16, 4), 512, 0, stream>>>(hb, wt_mlp2, buf_b, 4096, 1024, 4096, 1024);
  k_fmerge<<<4096, 256, 0, stream>>>(buf_b, x1, mgain, out);
  (void)in_sizes; (void)n_in; (void)out_size; (void)ws_size;
}

// Round 11
// 352.482 us; speedup vs baseline: 1.0076x; 1.0076x over previous
//
#include <hip/hip_runtime.h>

typedef __bf16 bf16_t;
typedef __attribute__((ext_vector_type(8))) __bf16 bh8;
typedef __attribute__((ext_vector_type(4))) __bf16 bh4;
typedef __attribute__((ext_vector_type(4))) float f32x4;

#define DEV static __device__ __forceinline__

typedef __attribute__((address_space(3))) void lds_void;
typedef const __attribute__((address_space(1))) void glb_void;

// async global->LDS, 16B per lane; LDS dest = wave-uniform base + lane*16
DEV void async16(const bf16_t* g, bf16_t* l) {
  __builtin_amdgcn_global_load_lds((glb_void*)g, (lds_void*)l, 16, 0, 0);
}

// raw barrier (no vmcnt(0)/lgkmcnt(0) drain like __syncthreads) + compiler fence
#define GBAR() asm volatile("s_barrier" ::: "memory")
#define VMW(n) asm volatile("s_waitcnt vmcnt(" #n ")" ::: "memory")

DEV f32x4 mfma16(bh8 a, bh8 b, f32x4 c) {
  return __builtin_amdgcn_mfma_f32_16x16x32_bf16(a, b, c, 0, 0, 0);
}

// swizzled LDS addressing for [R][64] bf16 tiles (rows = 128B): physical 16B-chunk
// = logical chunk ^ mask(row). mask7 for staged tiles (matches pre-swizzled
// global source), maskP adds row-bit3 so the 4 quads' C-layout writes hit 4
// distinct chunks.
DEV const bf16_t* lds7(const bf16_t* base, int row, int c) {
  return base + row * 64 + ((c ^ (row & 7)) << 3);
}
DEV bf16_t* ldsP(bf16_t* base, int row, int c) {
  int m = (row & 7) ^ ((row >> 3) & 1);
  return base + row * 64 + ((c ^ m) << 3);
}

// ---------- helpers ----------
DEV float wave_sum(float v) {
#pragma unroll
  for (int m = 32; m > 0; m >>= 1) v += __shfl_xor(v, m, 64);
  return v;
}

// assumes blockDim.x == 256 (4 waves)
DEV float block_sum(float v, float* sbuf) {
  v = wave_sum(v);
  int wid = threadIdx.x >> 6;
  if ((threadIdx.x & 63) == 0) sbuf[wid] = v;
  __syncthreads();
  float r = sbuf[0] + sbuf[1] + sbuf[2] + sbuf[3];
  __syncthreads();
  return r;
}

// ---------- zero the 8192-float ssq accumulator ----------
__global__ void k_zero(float* __restrict__ p) {
  p[blockIdx.x * 256 + threadIdx.x] = 0.f;
}

// ---------- fused transpose+cast (UNSCALED) + per-k-row sum-of-squares ----------
// Wt[n][k] = bf16(W[k][n]); ssq[base+k] += sum_n W[k][n]^2 (atomic, device scope).
// The row-norm scale is folded into the A-operand by each GEMM's producer kernel.
__global__ void k_wtrans_all(const float* __restrict__ w_cond, const float* __restrict__ w_qkv,
                             const float* __restrict__ w_out, const float* __restrict__ w_mlp1,
                             const float* __restrict__ w_mlp2, float* __restrict__ ssq,
                             bf16_t* __restrict__ wt_cond, bf16_t* __restrict__ wt_qkv,
                             bf16_t* __restrict__ wt_out, bf16_t* __restrict__ wt_mlp1,
                             bf16_t* __restrict__ wt_mlp2) {
  __shared__ float tile[64][65];
  int id = blockIdx.x;
  const float* W; bf16_t* Wt; int K, N, n0, k0, sb;
  if (id < 512)       { W=w_cond; Wt=wt_cond; K=1024; N=2048; sb=0;    int l=id;      n0=(l&31)*64; k0=(l>>5)*64; }
  else if (id < 1280) { W=w_qkv;  Wt=wt_qkv;  K=1024; N=3072; sb=1024; int l=id-512;  n0=(l%48)*64; k0=(l/48)*64; }
  else if (id < 1536) { W=w_out;  Wt=wt_out;  K=1024; N=1024; sb=2048; int l=id-1280; n0=(l&15)*64; k0=(l>>4)*64; }
  else if (id < 2560) { W=w_mlp1; Wt=wt_mlp1; K=1024; N=4096; sb=3072; int l=id-1536; n0=(l&63)*64; k0=(l>>6)*64; }
  else                { W=w_mlp2; Wt=wt_mlp2; K=4096; N=1024; sb=4096; int l=id-2560; n0=(l&15)*64; k0=(l>>4)*64; }
  int t = threadIdx.x;
#pragma unroll
  for (int i = t; i < 1024; i += 256) {
    int r = i >> 4, c4 = (i & 15) << 2;
    float4 w = *(const float4*)(W + (size_t)(k0 + r) * N + n0 + c4);
    tile[r][c4 + 0] = w.x;
    tile[r][c4 + 1] = w.y;
    tile[r][c4 + 2] = w.z;
    tile[r][c4 + 3] = w.w;
    float ss = w.x*w.x + w.y*w.y + w.z*w.z + w.w*w.w;
    // 16 consecutive lanes share row r -> reduce within the 16-lane group
#pragma unroll
    for (int m = 1; m < 16; m <<= 1) ss += __shfl_xor(ss, m, 64);
    if ((t & 15) == 0) atomicAdd(&ssq[sb + k0 + r], ss);
  }
  __syncthreads();
#pragma unroll
  for (int i = t; i < 1024; i += 256) {
    int rr = i >> 4, cc = (i & 15) << 2;
    bh4 o;
    o[0] = (bf16_t)tile[cc + 0][rr];
    o[1] = (bf16_t)tile[cc + 1][rr];
    o[2] = (bf16_t)tile[cc + 2][rr];
    o[3] = (bf16_t)tile[cc + 3][rr];
    *(bh4*)(Wt + (size_t)(n0 + rr) * K + k0 + cc) = o;
  }
}

// ---------- finalize scales: s = 1/((sqrt(ssq)*sqrt(N)+1e-4)*sqrt(K)) ----------
__global__ void k_sfin(const float* __restrict__ ssq, float* __restrict__ s) {
  int id = blockIdx.x * 256 + threadIdx.x;
  int N, K;
  if (id < 1024)      { N = 2048; K = 1024; }
  else if (id < 2048) { N = 3072; K = 1024; }
  else if (id < 3072) { N = 1024; K = 1024; }
  else if (id < 4096) { N = 4096; K = 1024; }
  else                { N = 1024; K = 4096; }
  float norm = sqrtf(ssq[id]);
  s[id] = 1.0f / ((norm * sqrtf((float)N) + 1e-4f) * sqrtf((float)K));
}

// ---------- conditioning: gs[b][j] = sum_k (silu(c)/0.596 * s_cond[k]) wt_cond[j][k] ----------
__global__ void k_cond(const float* __restrict__ c, const bf16_t* __restrict__ wt,
                       const float* __restrict__ sc, float* __restrict__ gs) {
  __shared__ float cc[4][1024];
  int t = threadIdx.x;
  for (int i = t; i < 4096; i += 256) {
    int b = i >> 10, col = i & 1023;
    float x = c[b * 1024 + col];
    float sig = 1.f / (1.f + __expf(-x));
    cc[b][col] = x * sig * (1.f / 0.596f) * sc[col];
  }
  __syncthreads();
  int wid = t >> 6, lane = t & 63;
  int j = blockIdx.x * 4 + wid;
  const bf16_t* wr = wt + (size_t)j * 1024;
  float acc0 = 0, acc1 = 0, acc2 = 0, acc3 = 0;
  for (int i = lane; i < 1024; i += 64) {
    float w = (float)wr[i];
    acc0 += cc[0][i] * w; acc1 += cc[1][i] * w;
    acc2 += cc[2][i] * w; acc3 += cc[3][i] * w;
  }
  float v0 = wave_sum(acc0), v1 = wave_sum(acc1), v2 = wave_sum(acc2), v3 = wave_sum(acc3);
  if (lane == 0) {
    gs[0 * 2048 + j] = v0; gs[1 * 2048 + j] = v1;
    gs[2 * 2048 + j] = v2; gs[3 * 2048 + j] = v3;
  }
}

// ---------- xc = bf16((pixel_norm(x)*(1+gain)+shift) * s_qkv[k]) ----------
__global__ void k_xcond(const float* __restrict__ x, const float* __restrict__ gs,
                        const float* __restrict__ sq, bf16_t* __restrict__ xc) {
  __shared__ float sbuf[4];
  int row = blockIdx.x, b = row >> 10, t = threadIdx.x;
  float4 v = ((const float4*)(x + (size_t)row * 1024))[t];
  float ss = v.x*v.x + v.y*v.y + v.z*v.z + v.w*v.w;
  float tot = block_sum(ss, sbuf);
  float r = rsqrtf(tot * (1.f/1024.f) + 1e-4f);
  float4 g  = ((const float4*)(gs + b * 2048))[t];
  float4 sh = ((const float4*)(gs + b * 2048 + 1024))[t];
  float4 sv = ((const float4*)sq)[t];
  bh4 o;
  o[0] = (bf16_t)((v.x * r * (1.f + g.x) + sh.x) * sv.x);
  o[1] = (bf16_t)((v.y * r * (1.f + g.y) + sh.y) * sv.y);
  o[2] = (bf16_t)((v.z * r * (1.f + g.z) + sh.z) * sv.z);
  o[3] = (bf16_t)((v.w * r * (1.f + g.w) + sh.w) * sv.w);
  *(bh4*)(xc + (size_t)row * 1024 + t * 4) = o;
}

// ---------- 256x256 8-phase bf16 MFMA GEMM (R1 schedule, measured best) ----------
//   ph1: 12 ds_read | stage A(kt+1)h0 -> rb^1
//   ph2:  4 ds_read | stage A(kt+1)h1 -> rb^1
//   ph3:  8 ds_read | stage B(kt+2)h0 -> rb   [B[rb] last read ph2]
//   ph4:  0 ds_read | stage B(kt+2)h1 -> rb
//   end ph4: vmcnt(4) -- A(kt+1)+B(kt+1) landed; B(kt+2)'s 4 loads in flight.
__global__ __launch_bounds__(512, 2) void k_gemm8(const bf16_t* __restrict__ A,
                                                  const bf16_t* __restrict__ Bt,
                                                  bf16_t* __restrict__ C,
                                                  int M, int N, int K, int klen) {
  __shared__ __attribute__((aligned(16))) bf16_t As[2][2][256][32];
  __shared__ __attribute__((aligned(16))) bf16_t Bs[2][2][256][32];
  // bijective XCD swizzle (requires nwg % 8 == 0; all our grids satisfy this)
  const int ntn = gridDim.x;
  const unsigned flat = blockIdx.x + ntn * blockIdx.y;
  const unsigned q = (ntn * gridDim.y) >> 3;
  const unsigned wg = (flat & 7) * q + (flat >> 3);
  const int m0 = (int)(wg / (unsigned)ntn) * 256;
  const int n0 = (int)(wg % (unsigned)ntn) * 256;
  const size_t kbeg = (size_t)blockIdx.z * klen;
  C += (size_t)blockIdx.z * M * N;
  const int t = threadIdx.x, lane = t & 63;
  const int wm = (t >> 6) >> 2, wn = (t >> 6) & 3;
  const int l15 = lane & 15, quad = lane >> 4;
  const int q8 = (quad ^ ((l15 >> 2) & 2)) * 8;   // swizzled slot of logical k-chunk
  const int rA = wm * 128 + l15;
  const int rB = wn * 64 + l15;
  const int sr = t >> 2;
  const int sc = ((t & 3) << 3) ^ ((t & 32) >> 1);   // ^16 when row bit3 set
  const int swv = (t >> 6) * 512;                    // wave-uniform LDS elem base
  const bf16_t* AgS = A + (size_t)(m0 + sr) * K + kbeg + sc;
  const bf16_t* BgS = Bt + (size_t)(n0 + sr) * K + kbeg + sc;
  const size_t rstep = (size_t)128 * K;
  const int NT = klen >> 6;
  f32x4 acc[8][4] = {};

#define STG_A(kt_, h_, bb_) { const bf16_t* g = AgS + (kt_) * 64 + (h_) * 32; \
    bf16_t* l = &As[bb_][h_][0][0] + swv; async16(g, l); async16(g + rstep, l + 4096); }
#define STG_B(kt_, h_, bb_) { const bf16_t* g = BgS + (kt_) * 64 + (h_) * 32; \
    bf16_t* l = &Bs[bb_][h_][0][0] + swv; async16(g, l); async16(g + rstep, l + 4096); }

  // prologue: B(0), A(0) -> buf0; B(1) -> buf1; wait all but B(1)'s 4 loads
  STG_B(0, 0, 0); STG_B(0, 1, 0);
  STG_A(0, 0, 0); STG_A(0, 1, 0);
  if (NT > 1) { STG_B(1, 0, 1); STG_B(1, 1, 1); VMW(4); } else { VMW(0); }
  GBAR();

  for (int kt = 0; kt < NT; ++kt) {
    const int bb = kt & 1;
    bh8 a[4][2], b[4][2];
    // ---- phase 1
#pragma unroll
    for (int m = 0; m < 4; ++m)
#pragma unroll
      for (int kc = 0; kc < 2; ++kc)
        a[m][kc] = *(const bh8*)&As[bb][kc][rA + m * 16][q8];
#pragma unroll
    for (int n = 0; n < 2; ++n)
#pragma unroll
      for (int kc = 0; kc < 2; ++kc)
        b[n][kc] = *(const bh8*)&Bs[bb][kc][rB + n * 16][q8];
    if (kt + 1 < NT) STG_A(kt + 1, 0, bb ^ 1);
    GBAR();
    __builtin_amdgcn_s_setprio(1);
#pragma unroll
    for (int m = 0; m < 4; ++m)
#pragma unroll
      for (int n = 0; n < 2; ++n)
#pragma unroll
        for (int kc = 0; kc < 2; ++kc)
          acc[m][n] = mfma16(a[m][kc], b[n][kc], acc[m][n]);
    __builtin_amdgcn_s_setprio(0);
    GBAR();
    // ---- phase 2
#pragma unroll
    for (int n = 0; n < 2; ++n)
#pragma unroll
      for (int kc = 0; kc < 2; ++kc)
        b[2 + n][kc] = *(const bh8*)&Bs[bb][kc][rB + (2 + n) * 16][q8];
    if (kt + 1 < NT) STG_A(kt + 1, 1, bb ^ 1);
    GBAR();
    __builtin_amdgcn_s_setprio(1);
#pragma unroll
    for (int m = 0; m < 4; ++m)
#pragma unroll
      for (int n = 0; n < 2; ++n)
#pragma unroll
        for (int kc = 0; kc < 2; ++kc)
          acc[m][2 + n] = mfma16(a[m][kc], b[2 + n][kc], acc[m][2 + n]);
    __builtin_amdgcn_s_setprio(0);
    GBAR();
    // ---- phase 3
#pragma unroll
    for (int m = 0; m < 4; ++m)
#pragma unroll
      for (int kc = 0; kc < 2; ++kc)
        a[m][kc] = *(const bh8*)&As[bb][kc][rA + 64 + m * 16][q8];
    if (kt + 2 < NT) STG_B(kt + 2, 0, bb);
    GBAR();
    __builtin_amdgcn_s_setprio(1);
#pragma unroll
    for (int m = 0; m < 4; ++m)
#pragma unroll
      for (int n = 0; n < 2; ++n)
#pragma unroll
        for (int kc = 0; kc < 2; ++kc)
          acc[4 + m][n] = mfma16(a[m][kc], b[n][kc], acc[4 + m][n]);
    __builtin_amdgcn_s_setprio(0);
    GBAR();
    // ---- phase 4
    if (kt + 2 < NT) STG_B(kt + 2, 1, bb);
    __builtin_amdgcn_s_setprio(1);
#pragma unroll
    for (int m = 0; m < 4; ++m)
#pragma unroll
      for (int n = 0; n < 2; ++n)
#pragma unroll
        for (int kc = 0; kc < 2; ++kc)
          acc[4 + m][2 + n] = mfma16(a[m][kc], b[2 + n][kc], acc[4 + m][2 + n]);
    __builtin_amdgcn_s_setprio(0);
    if (kt + 2 < NT) { VMW(4); } else { VMW(0); }
    GBAR();
  }
#undef STG_A
#undef STG_B

  const int cm = m0 + wm * 128 + quad * 4;
  const int cn = n0 + wn * 64 + l15;
#pragma unroll
  for (int m = 0; m < 8; ++m)
#pragma unroll
    for (int n = 0; n < 4; ++n)
#pragma unroll
      for (int r2 = 0; r2 < 4; ++r2)
        C[(size_t)(cm + m * 16 + r2) * N + cn + n * 16] = (bf16_t)acc[m][n][r2];
}

// ---------- 128x128-tile 2-phase GEMM (64 KiB LDS), used for the out-projection ----------
// (traffic win: no split-K partials; per-FLOP rate is lower than k_gemm8, so only
// used where the 256^2 kernel would need split-K)
__global__ __launch_bounds__(256, 2) void k_gemm2ph(const bf16_t* __restrict__ A,
                                                    const bf16_t* __restrict__ Bt,
                                                    bf16_t* __restrict__ C,
                                                    int M, int N, int K) {
  __shared__ __attribute__((aligned(16))) bf16_t As[2][2][128][32];
  __shared__ __attribute__((aligned(16))) bf16_t Bs[2][2][128][32];
  const int ntn = gridDim.x;
  const unsigned flat = blockIdx.x + ntn * blockIdx.y;
  const unsigned q = (ntn * gridDim.y) >> 3;
  const unsigned wg = (flat & 7) * q + (flat >> 3);
  const int m0 = (int)(wg / (unsigned)ntn) * 128;
  const int n0 = (int)(wg % (unsigned)ntn) * 128;
  const int t = threadIdx.x, lane = t & 63;
  const int wm = (t >> 6) >> 1, wn = (t >> 6) & 1;
  const int l15 = lane & 15, quad = lane >> 4;
  const int q8 = (quad ^ ((l15 >> 2) & 2)) * 8;
  const int rA = wm * 64 + l15;
  const int rB = wn * 64 + l15;
  const int sr = t >> 2;                             // 0..63
  const int sc = ((t & 3) << 3) ^ ((t & 32) >> 1);   // ^16 when row bit3 set
  const int swv = (t >> 6) * 512;                    // wave-uniform LDS elem base
  const bf16_t* AgS = A + (size_t)(m0 + sr) * K + sc;
  const bf16_t* BgS = Bt + (size_t)(n0 + sr) * K + sc;
  const size_t rstep = (size_t)64 * K;
  const int NT = K >> 6;
  f32x4 acc[4][4] = {};

#define STG_A(kt_, h_, bb_) { const bf16_t* g = AgS + (kt_) * 64 + (h_) * 32; \
    bf16_t* l = &As[bb_][h_][0][0] + swv; async16(g, l); async16(g + rstep, l + 2048); }
#define STG_B(kt_, h_, bb_) { const bf16_t* g = BgS + (kt_) * 64 + (h_) * 32; \
    bf16_t* l = &Bs[bb_][h_][0][0] + swv; async16(g, l); async16(g + rstep, l + 2048); }

  // prologue: A(0),B(0) -> buf0; B(1) -> buf1; keep B(1)'s 4 calls in flight
  STG_B(0, 0, 0); STG_B(0, 1, 0);
  STG_A(0, 0, 0); STG_A(0, 1, 0);
  if (NT > 1) { STG_B(1, 0, 1); STG_B(1, 1, 1); VMW(4); } else { VMW(0); }
  GBAR();

  for (int kt = 0; kt < NT; ++kt) {
    const int bb = kt & 1;
    bh8 a[4][2], b[4][2];
    // ---- phase 1: all 16 ds_read; stage A(kt+1) -> rb^1
#pragma unroll
    for (int m = 0; m < 4; ++m)
#pragma unroll
      for (int kc = 0; kc < 2; ++kc)
        a[m][kc] = *(const bh8*)&As[bb][kc][rA + m * 16][q8];
#pragma unroll
    for (int n = 0; n < 4; ++n)
#pragma unroll
      for (int kc = 0; kc < 2; ++kc)
        b[n][kc] = *(const bh8*)&Bs[bb][kc][rB + n * 16][q8];
    if (kt + 1 < NT) { STG_A(kt + 1, 0, bb ^ 1); STG_A(kt + 1, 1, bb ^ 1); }
    GBAR();
    __builtin_amdgcn_s_setprio(1);
#pragma unroll
    for (int m = 0; m < 4; ++m)
#pragma unroll
      for (int n = 0; n < 2; ++n)
#pragma unroll
        for (int kc = 0; kc < 2; ++kc)
          acc[m][n] = mfma16(a[m][kc], b[n][kc], acc[m][n]);
    __builtin_amdgcn_s_setprio(0);
    GBAR();
    // ---- phase 2: stage B(kt+2) -> rb (B[rb] reads all done ph1, barrier-separated)
    if (kt + 2 < NT) { STG_B(kt + 2, 0, bb); STG_B(kt + 2, 1, bb); }
    __builtin_amdgcn_s_setprio(1);
#pragma unroll
    for (int m = 0; m < 4; ++m)
#pragma unroll
      for (int n = 0; n < 2; ++n)
#pragma unroll
        for (int kc = 0; kc < 2; ++kc)
          acc[m][2 + n] = mfma16(a[m][kc], b[2 + n][kc], acc[m][2 + n]);
    __builtin_amdgcn_s_setprio(0);
    if (kt + 2 < NT) { VMW(4); } else { VMW(0); }
    GBAR();
  }
#undef STG_A
#undef STG_B

  const int cm = m0 + wm * 64 + quad * 4;
  const int cn = n0 + wn * 64 + l15;
#pragma unroll
  for (int m = 0; m < 4; ++m)
#pragma unroll
    for (int n = 0; n < 4; ++n)
#pragma unroll
      for (int r2 = 0; r2 < 4; ++r2)
        C[(size_t)(cm + m * 16 + r2) * N + cn + n * 16] = (bf16_t)acc[m][n][r2];
}

// ---------- qkv (bf16 in): pixel_norm per 1024-chunk + per-head L2 norm ----------
// writes qh/kh [B,NH,N,DH]; V is NOT materialized -- only its per-row scale rsv[row]
// (k_vtrans applies it while transposing straight out of the qkv buffer).
__global__ void k_qkvnorm(const bf16_t* __restrict__ qkv, bf16_t* __restrict__ qo,
                          bf16_t* __restrict__ ko, float* __restrict__ rsv) {
  __shared__ float sbuf[4];
  const int row = blockIdx.x, b = row >> 10, n = row & 1023, t = threadIdx.x;
  const bf16_t* rp = qkv + (size_t)row * 3072;
  bh4 q4 = *(const bh4*)(rp + t * 4);
  bh4 k4 = *(const bh4*)(rp + 1024 + t * 4);
  bh4 v4 = *(const bh4*)(rp + 2048 + t * 4);
  float4 q = {(float)q4[0], (float)q4[1], (float)q4[2], (float)q4[3]};
  float4 k = {(float)k4[0], (float)k4[1], (float)k4[2], (float)k4[3]};
  float4 v = {(float)v4[0], (float)v4[1], (float)v4[2], (float)v4[3]};
  float sq = q.x*q.x + q.y*q.y + q.z*q.z + q.w*q.w;
  float sk = k.x*k.x + k.y*k.y + k.z*k.z + k.w*k.w;
  float sv = v.x*v.x + v.y*v.y + v.z*v.z + v.w*v.w;
  float tq = block_sum(sq, sbuf);
  float tk = block_sum(sk, sbuf);
  float tv = block_sum(sv, sbuf);
  float rq = rsqrtf(tq * (1.f/1024.f) + 1e-4f);
  float rk = rsqrtf(tk * (1.f/1024.f) + 1e-4f);
  float rv = rsqrtf(tv * (1.f/1024.f) + 1e-4f);
  float hq = sq, hk = sk;   // per-head sums: 16 consecutive threads = one head (within a wave)
#pragma unroll
  for (int m = 1; m < 16; m <<= 1) { hq += __shfl_xor(hq, m, 64); hk += __shfl_xor(hk, m, 64); }
  float qs = rq * rsqrtf(rq*rq*hq + 1e-6f);
  float ks = rk * rsqrtf(rk*rk*hk + 1e-6f);
  int h = t >> 4, d = (t & 15) * 4;
  size_t base = ((size_t)(b * 16 + h) * 1024 + n) * 64 + d;
  bh4 oq, okk;
  oq[0]=(bf16_t)(q.x*qs); oq[1]=(bf16_t)(q.y*qs); oq[2]=(bf16_t)(q.z*qs); oq[3]=(bf16_t)(q.w*qs);
  okk[0]=(bf16_t)(k.x*ks); okk[1]=(bf16_t)(k.y*ks); okk[2]=(bf16_t)(k.z*ks); okk[3]=(bf16_t)(k.w*ks);
  *(bh4*)(qo + base) = oq;
  *(bh4*)(ko + base) = okk;
  if (t == 0) rsv[row] = rv;
}

// ---------- V transpose + pixel_norm: vt[bh][d][n] = bf16(qkv_v[b][n][h*64+d] * rsv[b*1024+n]) ----------
__global__ void k_vtrans(const bf16_t* __restrict__ qkv, const float* __restrict__ rsv,
                         bf16_t* __restrict__ vt) {
  __shared__ bf16_t tile[64][72];
  const int n0 = blockIdx.x * 64, bh = blockIdx.y;
  const int b = bh >> 4, h = bh & 15;
  const int t = threadIdx.x;
  const bf16_t* src = qkv + ((size_t)(b * 1024 + n0)) * 3072 + 2048 + h * 64;
#pragma unroll
  for (int i = t; i < 512; i += 256) {
    int r = i >> 3, p = (i & 7) * 8;
    float sc = rsv[b * 1024 + n0 + r];
    bh8 vv = *(const bh8*)(src + (size_t)r * 3072 + p);
    bh8 o8;
#pragma unroll
    for (int j = 0; j < 8; j++) o8[j] = (bf16_t)((float)vv[j] * sc);
    *(bh8*)&tile[r][p] = o8;
  }
  __syncthreads();
  bf16_t* dst = vt + (size_t)bh * 64 * 1024 + n0;
#pragma unroll
  for (int i = t; i < 512; i += 256) {
    int d = i & 63, nch = (i >> 6) * 8;
    bh8 o;
#pragma unroll
    for (int j = 0; j < 8; j++) o[j] = tile[nch + j][d];
    *(bh8*)(dst + (size_t)d * 1024 + nch) = o;
  }
}

// ---------- attention v2: Q-tile 128, async-LDS double-buffered K/V, XOR-swizzled tiles ----------
// output pre-scaled by s_out[col] (fold of the out-projection weight row-norm)
__global__ __launch_bounds__(256, 2) void k_attn(const bf16_t* __restrict__ Q,
                                                 const bf16_t* __restrict__ K,
                                                 const bf16_t* __restrict__ Vt_g,
                                                 const float* __restrict__ so,
                                                 bf16_t* __restrict__ O) {
  __shared__ __attribute__((aligned(16))) bf16_t Qs[128][64];
  __shared__ __attribute__((aligned(16))) bf16_t Ks[2][64][64];
  __shared__ __attribute__((aligned(16))) bf16_t Vt[2][64][64];   // [dh][kv]
  __shared__ __attribute__((aligned(16))) bf16_t Ps[128][64];
  const unsigned flat = blockIdx.x + 8u * blockIdx.y;   // grid = (8, 64)
  const int qt = (int)((flat >> 3) & 7);
  const int bh = (int)((flat & 7) * 8 + (flat >> 6));
  const int b = bh >> 4, h = bh & 15;
  const int t = threadIdx.x, lane = t & 63, wid = t >> 6;
  const int l15 = lane & 15, quad = lane >> 4;
  const int strip = wid * 32;
  const int srow = t >> 3;                       // 0..31 per 32-row group
  const int scol = ((t & 7) ^ (srow & 7)) << 3;  // elems
  const int swv = wid * 512;                     // wave-uniform LDS elem base (8 rows)
  const bf16_t* Qg = Q + ((size_t)bh * 1024 + qt * 128) * 64;
  const bf16_t* Kg = K + (size_t)bh * 1024 * 64;
  const bf16_t* Vg = Vt_g + (size_t)bh * 64 * 1024;   // [dh][n]

  // prologue: stage Q (4 calls), K0+V0 (4 calls); drain; barrier
#pragma unroll
  for (int c2 = 0; c2 < 4; ++c2)
    async16(Qg + (size_t)(c2 * 32 + srow) * 64 + scol, &Qs[0][0] + c2 * 2048 + swv);
#pragma unroll
  for (int r0 = 0; r0 < 64; r0 += 32) {
    async16(Kg + (size_t)(r0 + srow) * 64 + scol, &Ks[0][0][0] + r0 * 64 + swv);
    async16(Vg + (size_t)(r0 + srow) * 1024 + scol, &Vt[0][0][0] + r0 * 64 + swv);
  }
  VMW(0);
  GBAR();

  f32x4 o[2][4] = {};
  float rs[2][4] = {{}, {}};
  for (int kt = 0; kt < 16; ++kt) {
    const int bb = kt & 1;
    const int kv0 = kt * 64;
    if (kt < 15) {
#pragma unroll
      for (int r0 = 0; r0 < 64; r0 += 32) {
        async16(Kg + (size_t)(kv0 + 64 + r0 + srow) * 64 + scol,
                &Ks[bb ^ 1][0][0] + r0 * 64 + swv);
        async16(Vg + (size_t)(r0 + srow) * 1024 + kv0 + 64 + scol,
                &Vt[bb ^ 1][0][0] + r0 * 64 + swv);
      }
    }
    // ---- QK^T (this wave's 32-row strip vs 64 kv rows)
    f32x4 s[2][4] = {};
    bh8 aq[2][2], bk[4][2];
#pragma unroll
    for (int rf = 0; rf < 2; ++rf)
#pragma unroll
      for (int kc = 0; kc < 2; ++kc)
        aq[rf][kc] = *(const bh8*)lds7(&Qs[0][0], strip + rf * 16 + l15, kc * 4 + quad);
#pragma unroll
    for (int j = 0; j < 4; ++j)
#pragma unroll
      for (int kc = 0; kc < 2; ++kc)
        bk[j][kc] = *(const bh8*)lds7(&Ks[bb][0][0], j * 16 + l15, kc * 4 + quad);
    __builtin_amdgcn_s_setprio(1);
#pragma unroll
    for (int rf = 0; rf < 2; ++rf)
#pragma unroll
      for (int j = 0; j < 4; ++j)
#pragma unroll
        for (int kc = 0; kc < 2; ++kc)
          s[rf][j] = mfma16(aq[rf][kc], bk[j][kc], s[rf][j]);
    __builtin_amdgcn_s_setprio(0);
    // ---- P = exp(S/8) -> Ps (swizzled, wave-local strip); rs from bf16 P
#pragma unroll
    for (int rf = 0; rf < 2; ++rf)
#pragma unroll
      for (int j = 0; j < 4; ++j)
#pragma unroll
        for (int r = 0; r < 4; ++r) {
          float p = __expf(s[rf][j][r] * 0.125f);
          bf16_t pb = (bf16_t)p;
          rs[rf][r] += (float)pb;
          int prow = strip + rf * 16 + quad * 4 + r;
          ldsP(&Ps[0][0], prow, j * 2 + (l15 >> 3))[l15 & 7] = pb;
        }
    // ---- O += P @ V (wave reads only its own Ps strip: in-order LDS, no barrier)
    bh8 ap[2][2], bv[4][2];
#pragma unroll
    for (int rf = 0; rf < 2; ++rf)
#pragma unroll
      for (int kc = 0; kc < 2; ++kc)
        ap[rf][kc] = *(const bh8*)ldsP(&Ps[0][0], strip + rf * 16 + l15, kc * 4 + quad);
#pragma unroll
    for (int j = 0; j < 4; ++j)
#pragma unroll
      for (int kc = 0; kc < 2; ++kc)
        bv[j][kc] = *(const bh8*)lds7(&Vt[bb][0][0], j * 16 + l15, kc * 4 + quad);
    __builtin_amdgcn_s_setprio(1);
#pragma unroll
    for (int rf = 0; rf < 2; ++rf)
#pragma unroll
      for (int j = 0; j < 4; ++j)
#pragma unroll
        for (int kc = 0; kc < 2; ++kc)
          o[rf][j] = mfma16(ap[rf][kc], bv[j][kc], o[rf][j]);
    __builtin_amdgcn_s_setprio(0);
    if (kt < 15) { VMW(0); GBAR(); }
  }
  // ---- finalize: rowsum over the 16 column-lanes; apply inv-sum and s_out[col]
  float soj[4];
#pragma unroll
  for (int j = 0; j < 4; ++j) soj[j] = so[h * 64 + j * 16 + l15];
#pragma unroll
  for (int rf = 0; rf < 2; ++rf)
#pragma unroll
    for (int r = 0; r < 4; ++r) {
      float v = rs[rf][r];
      v += __shfl_xor(v, 1, 64); v += __shfl_xor(v, 2, 64);
      v += __shfl_xor(v, 4, 64); v += __shfl_xor(v, 8, 64);
      float inv = 1.f / v;
      int n = qt * 128 + strip + rf * 16 + quad * 4 + r;
#pragma unroll
      for (int j = 0; j < 4; ++j)
        O[((size_t)b * 1024 + n) * 1024 + h * 64 + j * 16 + l15] =
            (bf16_t)(o[rf][j][r] * inv * soj[j]);
    }
}

// ---------- x1 = mp_add(x, pixel_norm(y)*exp(ag)); xc2 = bf16(cond(x1) * s_mlp1) ----------
__global__ void k_amerge(const bf16_t* __restrict__ y, const float* __restrict__ x,
                         const float* __restrict__ gs, const float* __restrict__ again,
                         const float* __restrict__ sm1,
                         bf16_t* __restrict__ x1, bf16_t* __restrict__ xc2) {
  __shared__ float sbuf[4];
  int row = blockIdx.x, b = row >> 10, t = threadIdx.x;
  bh4 a = *(const bh4*)(y + (size_t)row * 1024 + t * 4);
  float4 yv = {(float)a[0], (float)a[1], (float)a[2], (float)a[3]};
  float4 xv = ((const float4*)(x + (size_t)row * 1024))[t];
  float ss = yv.x*yv.x + yv.y*yv.y + yv.z*yv.z + yv.w*yv.w;
  float tot = block_sum(ss, sbuf);
  float r = rsqrtf(tot * (1.f/1024.f) + 1e-4f);
  float ag = __expf(again[0]);
  const float C1 = 0.7f / 0.76157731059f, C2 = 0.3f / 0.76157731059f; // /sqrt(0.58)
  float4 xo;
  xo.x = C1 * xv.x + C2 * (yv.x * r * ag);
  xo.y = C1 * xv.y + C2 * (yv.y * r * ag);
  xo.z = C1 * xv.z + C2 * (yv.z * r * ag);
  xo.w = C1 * xv.w + C2 * (yv.w * r * ag);
  bh4 x1o;
  x1o[0] = (bf16_t)xo.x; x1o[1] = (bf16_t)xo.y; x1o[2] = (bf16_t)xo.z; x1o[3] = (bf16_t)xo.w;
  *(bh4*)(x1 + (size_t)row * 1024 + t * 4) = x1o;
  float ss1 = xo.x*xo.x + xo.y*xo.y + xo.z*xo.z + xo.w*xo.w;
  float tot1 = block_sum(ss1, sbuf);
  float r1 = rsqrtf(tot1 * (1.f/1024.f) + 1e-4f);
  float4 g  = ((const float4*)(gs + b * 2048))[t];
  float4 sh = ((const float4*)(gs + b * 2048 + 1024))[t];
  float4 sv = ((const float4*)sm1)[t];
  bh4 o;
  o[0] = (bf16_t)((xo.x * r1 * (1.f + g.x) + sh.x) * sv.x);
  o[1] = (bf16_t)((xo.y * r1 * (1.f + g.y) + sh.y) * sv.y);
  o[2] = (bf16_t)((xo.z * r1 * (1.f + g.z) + sh.z) * sv.z);
  o[3] = (bf16_t)((xo.w * r1 * (1.f + g.w) + sh.w) * sv.w);
  *(bh4*)(xc2 + (size_t)row * 1024 + t * 4) = o;
}

// ---------- h = bf16(mp_silu(pixel_norm(hf)) * s_mlp2[k]) over 4096-wide rows ----------
__global__ void k_mlpnorm(const bf16_t* __restrict__ hf, const float* __restrict__ sm2,
                          bf16_t* __restrict__ hb) {
  __shared__ float sbuf[4];
  int row = blockIdx.x, t = threadIdx.x;
  const bf16_t* rp = hf + (size_t)row * 4096;
  float4 v[4]; float ss = 0.f;
#pragma unroll
  for (int i = 0; i < 4; i++) {
    bh4 bv = *(const bh4*)(rp + (t + 256 * i) * 4);
    v[i].x = (float)bv[0]; v[i].y = (float)bv[1]; v[i].z = (float)bv[2]; v[i].w = (float)bv[3];
    ss += v[i].x*v[i].x + v[i].y*v[i].y + v[i].z*v[i].z + v[i].w*v[i].w;
  }
  float tot = block_sum(ss, sbuf);
  float r = rsqrtf(tot * (1.f/4096.f) + 1e-4f);
#pragma unroll
  for (int i = 0; i < 4; i++) {
    float a[4] = {v[i].x, v[i].y, v[i].z, v[i].w};
    float4 s4 = ((const float4*)sm2)[t + 256 * i];
    float sa[4] = {s4.x, s4.y, s4.z, s4.w};
    bh4 o;
#pragma unroll
    for (int j = 0; j < 4; j++) {
      float u = a[j] * r;
      float sig = 1.f / (1.f + __expf(-u));
      o[j] = (bf16_t)(u * sig * (1.f / 0.596f) * sa[j]);
    }
    *(bh4*)(hb + (size_t)row * 4096 + (t + 256 * i) * 4) = o;
  }
}

// ---------- out = mp_add(x1, pixel_norm(sum of 4 partials)*exp(mg)) ----------
__global__ void k_fmerge(const bf16_t* __restrict__ y, const bf16_t* __restrict__ x1,
                         const float* __restrict__ mgain, float* __restrict__ out) {
  __shared__ float sbuf[4];
  int row = blockIdx.x, t = threadIdx.x;
  const size_t PS = (size_t)4096 * 1024;
  float4 yv = {0.f, 0.f, 0.f, 0.f};
#pragma unroll
  for (int p = 0; p < 4; p++) {
    bh4 yp = *(const bh4*)(y + p * PS + (size_t)row * 1024 + t * 4);
    yv.x += (float)yp[0]; yv.y += (float)yp[1]; yv.z += (float)yp[2]; yv.w += (float)yp[3];
  }
  bh4 xb = *(const bh4*)(x1 + (size_t)row * 1024 + t * 4);
  float4 xv = {(float)xb[0], (float)xb[1], (float)xb[2], (float)xb[3]};
  float ss = yv.x*yv.x + yv.y*yv.y + yv.z*yv.z + yv.w*yv.w;
  float tot = block_sum(ss, sbuf);
  float r = rsqrtf(tot * (1.f/1024.f) + 1e-4f);
  float mg = __expf(mgain[0]);
  const float C1 = 0.7f / 0.76157731059f, C2 = 0.3f / 0.76157731059f;
  float4 o;
  o.x = C1 * xv.x + C2 * (yv.x * r * mg);
  o.y = C1 * xv.y + C2 * (yv.y * r * mg);
  o.z = C1 * xv.z + C2 * (yv.z * r * mg);
  o.w = C1 * xv.w + C2 * (yv.w * r * mg);
  ((float4*)(out + (size_t)row * 1024))[t] = o;
}

// ---------- launch ----------
extern "C" void kernel_launch(void* const* d_in, const int* in_sizes, int n_in,
                              void* d_out, int out_size, void* d_ws, size_t ws_size,
                              hipStream_t stream) {
  const float* x      = (const float*)d_in[0];
  const float* c      = (const float*)d_in[1];
  const float* w_cond = (const float*)d_in[2];
  const float* w_qkv  = (const float*)d_in[3];
  const float* w_out  = (const float*)d_in[4];
  const float* w_mlp1 = (const float*)d_in[5];
  const float* w_mlp2 = (const float*)d_in[6];
  const float* again  = (const float*)d_in[7];
  const float* mgain  = (const float*)d_in[8];
  float* out = (float*)d_out;
  char* ws = (char*)d_ws;

  // ws layout (bytes)
  bf16_t* wt_cond = (bf16_t*)(ws + 0);                    //  4 MB [2048,1024]
  bf16_t* wt_qkv  = (bf16_t*)(ws + 4194304);              //  6 MB [3072,1024]
  bf16_t* wt_out  = (bf16_t*)(ws + 10485760);             //  2 MB [1024,1024]
  bf16_t* wt_mlp1 = (bf16_t*)(ws + 12582912);             //  8 MB [4096,1024]
  bf16_t* wt_mlp2 = (bf16_t*)(ws + 20971520);             //  8 MB [1024,4096]
  float*  sn      = (float*)(ws + 29360128);              //  32 KB (5 scale arrays, packed)
  float*  gs      = (float*)(ws + 29392896);              //  32 KB [4,2048]; doubles as ssq before k_cond
  bf16_t* xc      = (bf16_t*)(ws + 29425664);             //  8 MB (xc, later xc2)
  bf16_t* qh      = (bf16_t*)(ws + 37814272);             //  8 MB
  bf16_t* kh      = (bf16_t*)(ws + 46202880);             //  8 MB
  float*  rsv     = (float*)(ws + 54591488);              //  16 KB (per-row V scales)
  bf16_t* xattn   = (bf16_t*)(ws + 62980096);             //  8 MB
  bf16_t* hb      = (bf16_t*)(ws + 37814272);             // 32 MB = qh..xattn reused after consumed
  bf16_t* x1      = (bf16_t*)(ws + 71368704);             //  8 MB (bf16 residual)
  bf16_t* vt      = (bf16_t*)(ws + 79757312);             //  8 MB (V^T [bh][dh][n])
  bf16_t* buf_b   = (bf16_t*)(ws + 88145920);             // 32 MB bf16: qkv / partials / h
  float*  ssq     = gs;                                   // alias: dead before k_cond writes gs

  // weight prep: single pass over fp32 weights (transpose+cast + row sum-of-squares),
  // then finalize scales. Scales are folded into A-operands by the producer kernels.
  k_zero<<<32, 256, 0, stream>>>(ssq);
  k_wtrans_all<<<3584, 256, 0, stream>>>(w_cond, w_qkv, w_out, w_mlp1, w_mlp2, ssq,
                                         wt_cond, wt_qkv, wt_out, wt_mlp1, wt_mlp2);
  k_sfin<<<32, 256, 0, stream>>>(ssq, sn);

  // conditioning (cc pre-scaled by s_cond)
  k_cond<<<512, 256, 0, stream>>>(c, wt_cond, sn, gs);
  // attention branch
  k_xcond<<<4096, 256, 0, stream>>>(x, gs, sn + 1024, xc);
  k_gemm8<<<dim3(12, 16, 1), 512, 0, stream>>>(xc, wt_qkv, buf_b, 4096, 3072, 1024, 1024);
  k_qkvnorm<<<4096, 256, 0, stream>>>(buf_b, qh, kh, rsv);
  k_vtrans<<<dim3(16, 64), 256, 0, stream>>>(buf_b, rsv, vt);
  k_attn<<<dim3(8, 64), 256, 0, stream>>>(qh, kh, vt, sn + 2048, xattn);
  // out-projection: 128x128-tile, no split-K, full fill -> single 8 MB output
  k_gemm2ph<<<dim3(8, 32), 256, 0, stream>>>(xattn, wt_out, buf_b, 4096, 1024, 1024);
  k_amerge<<<4096, 256, 0, stream>>>(buf_b, x, gs, again, sn + 3072, x1, xc);
  // MLP branch (mlp1 back on the proven k_gemm8)
  k_gemm8<<<dim3(16, 16, 1), 512, 0, stream>>>(xc, wt_mlp1, buf_b, 4096, 4096, 1024, 1024);
  k_mlpnorm<<<4096, 256, 0, stream>>>(buf_b, sn + 4096, hb);
  k_gemm8<<<dim3(4, 16, 4), 512, 0, stream>>>(hb, wt_mlp2, buf_b, 4096, 1024, 4096, 1024);
  k_fmerge<<<4096, 256, 0, stream>>>(buf_b, x1, mgain, out);
  (void)in_sizes; (void)n_in; (void)out_size; (void)ws_size;
}